// Round 1
// baseline (639.999 us; speedup 1.0000x reference)
//
#include <hip/hip_runtime.h>
#include <hip/hip_bf16.h>
#include <math.h>

#define N 4096
#define G 2048
#define H1 512
#define H2 128
#define HEADS 8
#define EMB 16
#define C 20
#define S 4
#define CH 64
#define CIN_D (H2 + EMB)   // 144
#define CAP 128
#define EPSV 1e-6f

// ---------------- CSR build from dense binary adjacency ----------------
__global__ void build_csr(const float* __restrict__ adj, int* __restrict__ col_idx,
                          int* __restrict__ row_cnt) {
    int i = blockIdx.x;
    int lane = threadIdx.x;  // 64
    int cnt = 0;
    const float* row = adj + (size_t)i * N;
    int* cols = col_idx + (size_t)i * CAP;
    for (int c0 = 0; c0 < N; c0 += 64) {
        float v = row[c0 + lane];
        unsigned long long m = __ballot(v != 0.f);
        int pos = __popcll(m & ((1ull << lane) - 1ull));
        if (v != 0.f) {
            int idx = cnt + pos;
            if (idx < CAP) cols[idx] = c0 + lane;
        }
        cnt += __popcll(m);
    }
    if (lane == 0) row_cnt[i] = cnt < CAP ? cnt : CAP;
}

// ---------------- generic fp32 GEMM: Cmat[M,Nc] = A[M,K] @ B[Nc,K]^T + bias ----------------
#define BM 64
#define BN 64
#define BK 16
__global__ void gemm_bias(const float* __restrict__ A, const float* __restrict__ B,
                          const float* __restrict__ bias, float* __restrict__ Cmat,
                          int M, int Nc, int K) {
    __shared__ float As[BK][BM + 1];
    __shared__ float Bs[BK][BN + 1];
    int bn = blockIdx.x, bm = blockIdx.y;
    int t = threadIdx.x;                 // 256
    int tm = t >> 4, tn = t & 15;        // 16x16 thread grid, 4x4 micro-tile
    float acc[4][4] = {};
    for (int k0 = 0; k0 < K; k0 += BK) {
        #pragma unroll
        for (int l = 0; l < 4; ++l) {
            int idx = t * 4 + l;
            int m = idx >> 4, k = idx & 15;
            As[k][m] = A[(size_t)(bm * BM + m) * K + k0 + k];
        }
        #pragma unroll
        for (int l = 0; l < 4; ++l) {
            int idx = t * 4 + l;
            int n = idx >> 4, k = idx & 15;
            Bs[k][n] = B[(size_t)(bn * BN + n) * K + k0 + k];
        }
        __syncthreads();
        #pragma unroll
        for (int k = 0; k < BK; ++k) {
            float a[4], b[4];
            #pragma unroll
            for (int x = 0; x < 4; ++x) a[x] = As[k][tm * 4 + x];
            #pragma unroll
            for (int y = 0; y < 4; ++y) b[y] = Bs[k][tn * 4 + y];
            #pragma unroll
            for (int x = 0; x < 4; ++x)
                #pragma unroll
                for (int y = 0; y < 4; ++y) acc[x][y] += a[x] * b[y];
        }
        __syncthreads();
    }
    #pragma unroll
    for (int x = 0; x < 4; ++x) {
        int row = bm * BM + tm * 4 + x;
        #pragma unroll
        for (int y = 0; y < 4; ++y) {
            int col = bn * BN + tn * 4 + y;
            Cmat[(size_t)row * Nc + col] = acc[x][y] + bias[col];
        }
    }
}

// ---------------- per-head attention dot products hv0/hv1 ----------------
__global__ void head_dots(const float* __restrict__ Hlin, const float* __restrict__ v0,
                          const float* __restrict__ v1, float* __restrict__ hv0,
                          float* __restrict__ hv1) {
    int i = blockIdx.x;
    int lane = threadIdx.x;  // 64
    #pragma unroll
    for (int h = 0; h < HEADS; ++h) {
        float v = Hlin[(size_t)i * H1 + h * CH + lane];
        float p0 = v * v0[h * CH + lane];
        float p1 = v * v1[h * CH + lane];
        #pragma unroll
        for (int m = 32; m; m >>= 1) {
            p0 += __shfl_xor(p0, m);
            p1 += __shfl_xor(p1, m);
        }
        if (lane == 0) {
            hv0[i * HEADS + h] = p0;
            hv1[i * HEADS + h] = p1;
        }
    }
}

// ---------------- sparse GAT aggregation + elu ----------------
__global__ void attn_agg(const float* __restrict__ Hlin, const float* __restrict__ hv0,
                         const float* __restrict__ hv1, const int* __restrict__ col_idx,
                         const int* __restrict__ row_cnt, float* __restrict__ out) {
    int i = blockIdx.x;
    int tid = threadIdx.x;   // 512 threads: head = tid/64, channel = tid%64
    int h = tid >> 6;
    float a0 = hv0[i * HEADS + h];
    int cnt = row_cnt[i];
    const int* cols = col_idx + (size_t)i * CAP;
    float den = 0.f, acc = 0.f;
    for (int e = 0; e < cnt; ++e) {
        int j = cols[e];
        float x = a0 + hv1[j * HEADS + h];
        float sg = 1.f / (1.f + expf(-x)) - 0.5f;
        float w = expf(sg);
        den += w;
        acc += w * Hlin[(size_t)j * H1 + tid];
    }
    den = (den == 0.f) ? 1.f : den;
    float o = acc / den;
    out[(size_t)i * H1 + tid] = (o > 0.f) ? o : expm1f(o);
}

// ---------------- per-node: beta softmax, alpha, Xd = concat(Z, emb) ----------------
__global__ void pernode(const float* __restrict__ Z, const float* __restrict__ emb_table,
                        const int* __restrict__ slab, const float* __restrict__ Wb,
                        const float* __restrict__ bb, const float* __restrict__ Wa,
                        const float* __restrict__ ba, float* __restrict__ beta,
                        float* __restrict__ alpha, float* __restrict__ Xd) {
    int i = blockIdx.x;
    int lane = threadIdx.x;  // 64
    __shared__ float sZ[H2];
    __shared__ float sE[EMB];
    __shared__ float sLog[C];
    sZ[lane] = Z[(size_t)i * H2 + lane];
    sZ[64 + lane] = Z[(size_t)i * H2 + 64 + lane];
    int s = slab[i];
    if (lane < EMB) sE[lane] = emb_table[s * EMB + lane];
    __syncthreads();
    // Xd = raw concat(Z, emb)
    Xd[(size_t)i * CIN_D + lane] = sZ[lane];
    Xd[(size_t)i * CIN_D + 64 + lane] = sZ[64 + lane];
    if (lane < EMB) Xd[(size_t)i * CIN_D + H2 + lane] = sE[lane];
    // beta logits over elu(Z)
    if (lane < C) {
        float acc = bb[lane];
        for (int k = 0; k < H2; ++k) {
            float z = sZ[k];
            float e = z > 0.f ? z : expm1f(z);
            acc += e * Wb[lane * H2 + k];
        }
        sLog[lane] = acc;
    }
    __syncthreads();
    if (lane == 0) {
        float mx = sLog[0];
        for (int c = 1; c < C; ++c) mx = fmaxf(mx, sLog[c]);
        float sm = 0.f;
        for (int c = 0; c < C; ++c) { float e = expf(sLog[c] - mx); sLog[c] = e; sm += e; }
        for (int c = 0; c < C; ++c) sLog[c] /= sm;
    }
    __syncthreads();
    if (lane < C) beta[(size_t)i * C + lane] = sLog[lane];
    // alpha = elu(concat(Z,emb)) . Wa + ba
    float x0 = sZ[lane];        x0 = x0 > 0.f ? x0 : expm1f(x0);
    float x1 = sZ[64 + lane];   x1 = x1 > 0.f ? x1 : expm1f(x1);
    float p = x0 * Wa[lane] + x1 * Wa[64 + lane];
    if (lane < EMB) {
        float x2 = sE[lane];    x2 = x2 > 0.f ? x2 : expm1f(x2);
        p += x2 * Wa[H2 + lane];
    }
    #pragma unroll
    for (int m = 32; m; m >>= 1) p += __shfl_xor(p, m);
    if (lane == 0) alpha[i] = p + ba[0];
}

// ---------------- precompute per-(slice,gene) theta tables ----------------
__global__ void theta_tables(const float* __restrict__ logtheta, float* __restrict__ th_v,
                             float* __restrict__ lg_th, float* __restrict__ thlog_th) {
    int idx = blockIdx.x * blockDim.x + threadIdx.x;
    if (idx >= S * G) return;
    float th = expf(logtheta[idx]);
    th_v[idx] = th;
    lg_th[idx] = lgammaf(th + EPSV);
    thlog_th[idx] = th * logf(th + EPSV);
}

// ---------------- per-row NB loss + reconstruction sq-norm ----------------
__global__ void loss_row(const float* __restrict__ Xr, const float* __restrict__ nf,
                         const float* __restrict__ cm, const float* __restrict__ beta,
                         const float* __restrict__ basis, const float* __restrict__ alpha,
                         const float* __restrict__ lib, const int* __restrict__ slab,
                         const float* __restrict__ gamma, const float* __restrict__ th_v,
                         const float* __restrict__ lg_th, const float* __restrict__ thlog_th,
                         float* __restrict__ ll_row, float* __restrict__ sq_row) {
    int i = blockIdx.x;
    int t = threadIdx.x;  // 256
    __shared__ float sb[C];
    if (t < C) sb[t] = beta[(size_t)i * C + t];
    __syncthreads();
    int s = slab[i];
    float A = alpha[i], L = lib[i];
    float all = 0.f, asq = 0.f;
    for (int g = t; g < G; g += 256) {
        float bd = 0.f;
        #pragma unroll
        for (int c = 0; c < C; ++c) bd += sb[c] * basis[c * G + g];
        float loglam = logf(bd + EPSV) + A + gamma[s * G + g];
        float mu = L * expf(loglam);
        float th = th_v[s * G + g];
        float k = cm[(size_t)i * G + g];
        float lthmu = logf(th + mu + EPSV);
        float ll = lgammaf(k + th + EPSV) - lg_th[s * G + g]
                 + thlog_th[s * G + g] - th * lthmu
                 + k * logf(mu + EPSV) - k * lthmu;
        all += ll;
        float d = nf[(size_t)i * G + g] - Xr[(size_t)i * G + g];
        asq += d * d;
    }
    __shared__ float r1[256], r2[256];
    r1[t] = all; r2[t] = asq;
    __syncthreads();
    for (int o = 128; o; o >>= 1) {
        if (t < o) { r1[t] += r1[t + o]; r2[t] += r2[t + o]; }
        __syncthreads();
    }
    if (t == 0) { ll_row[i] = r1[0]; sq_row[i] = r2[0]; }
}

// ---------------- final scalar ----------------
__global__ void finalize(const float* __restrict__ ll_row, const float* __restrict__ sq_row,
                         float* __restrict__ out) {
    int t = threadIdx.x;  // 256
    float a = 0.f, b = 0.f;
    for (int r = t; r < N; r += 256) {
        a += ll_row[r];
        b += sqrtf(sq_row[r]);
    }
    __shared__ float r1[256], r2[256];
    r1[t] = a; r2[t] = b;
    __syncthreads();
    for (int o = 128; o; o >>= 1) {
        if (t < o) { r1[t] += r1[t + o]; r2[t] += r2[t + o]; }
        __syncthreads();
    }
    if (t == 0) out[0] = -(r1[0] / (float)N) + 0.1f * (r2[0] / (float)N);
}

extern "C" void kernel_launch(void* const* d_in, const int* in_sizes, int n_in,
                              void* d_out, int out_size, void* d_ws, size_t ws_size,
                              hipStream_t stream) {
    const float* adj       = (const float*)d_in[0];
    const float* node_f    = (const float*)d_in[1];
    const float* count_m   = (const float*)d_in[2];
    const float* lib       = (const float*)d_in[3];
    const int*   slab      = (const int*)d_in[4];
    const float* basis     = (const float*)d_in[5];
    const float* We1       = (const float*)d_in[6];
    const float* be1       = (const float*)d_in[7];
    const float* v0e1      = (const float*)d_in[8];
    const float* v1e1      = (const float*)d_in[9];
    const float* W2        = (const float*)d_in[10];
    const float* b2        = (const float*)d_in[11];
    const float* Wd1       = (const float*)d_in[12];
    const float* bd1       = (const float*)d_in[13];
    const float* v0d1      = (const float*)d_in[14];
    const float* v1d1      = (const float*)d_in[15];
    const float* Wd2       = (const float*)d_in[16];
    const float* bd2       = (const float*)d_in[17];
    const float* Wa        = (const float*)d_in[18];
    const float* ba        = (const float*)d_in[19];
    const float* Wb        = (const float*)d_in[20];
    const float* bb        = (const float*)d_in[21];
    const float* gamma     = (const float*)d_in[22];
    const float* logtheta  = (const float*)d_in[23];
    const float* emb_table = (const float*)d_in[24];
    float* out = (float*)d_out;

    char* w = (char*)d_ws;
    int* col_idx = (int*)w;      w += (size_t)N * CAP * 4;
    int* row_cnt = (int*)w;      w += (size_t)N * 4;
    float* bufA  = (float*)w;    w += (size_t)N * H1 * 4;   // Henc_lin, then Hd_lin
    float* bufB  = (float*)w;    w += (size_t)N * H1 * 4;   // Hgat_enc, then Hd_act
    float* Z     = (float*)w;    w += (size_t)N * H2 * 4;
    float* Xd    = (float*)w;    w += (size_t)N * CIN_D * 4;
    float* beta  = (float*)w;    w += (size_t)N * C * 4;
    float* alpha = (float*)w;    w += (size_t)N * 4;
    float* hv0   = (float*)w;    w += (size_t)N * HEADS * 4;
    float* hv1   = (float*)w;    w += (size_t)N * HEADS * 4;
    float* th_v  = (float*)w;    w += (size_t)S * G * 4;
    float* lg_th = (float*)w;    w += (size_t)S * G * 4;
    float* thlog = (float*)w;    w += (size_t)S * G * 4;
    float* Xrec  = (float*)w;    w += (size_t)N * G * 4;    // 32 MB
    float* ll_row = (float*)w;   w += (size_t)N * 4;
    float* sq_row = (float*)w;   w += (size_t)N * 4;

    // 0. CSR from dense adjacency
    hipLaunchKernelGGL(build_csr, dim3(N), dim3(64), 0, stream, adj, col_idx, row_cnt);
    // 0b. theta tables
    hipLaunchKernelGGL(theta_tables, dim3((S * G + 255) / 256), dim3(256), 0, stream,
                       logtheta, th_v, lg_th, thlog);
    // 1. encoder linear: Henc = node_feats @ We1^T + be1  [N, 512]
    hipLaunchKernelGGL(gemm_bias, dim3(H1 / BN, N / BM), dim3(256), 0, stream,
                       node_f, We1, be1, bufA, N, H1, G);
    // 2. encoder attention dots
    hipLaunchKernelGGL(head_dots, dim3(N), dim3(64), 0, stream, bufA, v0e1, v1e1, hv0, hv1);
    // 3. encoder sparse GAT aggregation + elu
    hipLaunchKernelGGL(attn_agg, dim3(N), dim3(H1), 0, stream,
                       bufA, hv0, hv1, col_idx, row_cnt, bufB);
    // 4. Z = Hgat @ W2^T + b2  [N, 128]
    hipLaunchKernelGGL(gemm_bias, dim3(H2 / BN, N / BM), dim3(256), 0, stream,
                       bufB, W2, b2, Z, N, H2, H1);
    // 5. per-node: beta, alpha, Xd
    hipLaunchKernelGGL(pernode, dim3(N), dim3(64), 0, stream,
                       Z, emb_table, slab, Wb, bb, Wa, ba, beta, alpha, Xd);
    // 6. decoder linear: Hd = Xd @ Wd1^T + bd1  [N, 512]
    hipLaunchKernelGGL(gemm_bias, dim3(H1 / BN, N / BM), dim3(256), 0, stream,
                       Xd, Wd1, bd1, bufA, N, H1, CIN_D);
    // 7. decoder attention dots
    hipLaunchKernelGGL(head_dots, dim3(N), dim3(64), 0, stream, bufA, v0d1, v1d1, hv0, hv1);
    // 8. decoder sparse GAT aggregation + elu
    hipLaunchKernelGGL(attn_agg, dim3(N), dim3(H1), 0, stream,
                       bufA, hv0, hv1, col_idx, row_cnt, bufB);
    // 9. X_recon = Hd_act @ Wd2^T + bd2  [N, 2048]
    hipLaunchKernelGGL(gemm_bias, dim3(G / BN, N / BM), dim3(256), 0, stream,
                       bufB, Wd2, bd2, Xrec, N, G, H1);
    // 10. per-row NB loss + reconstruction norm
    hipLaunchKernelGGL(loss_row, dim3(N), dim3(256), 0, stream,
                       Xrec, node_f, count_m, beta, basis, alpha, lib, slab, gamma,
                       th_v, lg_th, thlog, ll_row, sq_row);
    // 11. final scalar
    hipLaunchKernelGGL(finalize, dim3(1), dim3(256), 0, stream, ll_row, sq_row, out);
}

// Round 3
// 338.951 us; speedup vs baseline: 1.8882x; 1.8882x over previous
//
#include <hip/hip_runtime.h>
#include <hip/hip_bf16.h>
#include <math.h>

#define N 4096
#define G 2048
#define H1 512
#define H2 128
#define HEADS 8
#define EMB 16
#define C 20
#define S 4
#define CH 64
#define CIN_D (H2 + EMB)   // 144
#define KD_PAD 160         // CIN_D padded to multiple of 32
#define CAP 128
#define EPSV 1e-6f
#define KMAX 50

typedef __attribute__((ext_vector_type(8))) short short8;
typedef __attribute__((ext_vector_type(8))) short bf16x8;
typedef __attribute__((ext_vector_type(4))) float f32x4;

__device__ __forceinline__ unsigned short f2b(float x) {
    __hip_bfloat16 h = __float2bfloat16(x);
    return *reinterpret_cast<unsigned short*>(&h);
}

// ---------------- CSR build from dense binary adjacency (float4 loads) ----------------
__global__ void build_csr(const float* __restrict__ adj, int* __restrict__ col_idx,
                          int* __restrict__ row_cnt) {
    int i = blockIdx.x;
    int lane = threadIdx.x;  // 64
    int cnt = 0;
    const float4* row4 = (const float4*)(adj + (size_t)i * N);
    int* cols = col_idx + (size_t)i * CAP;
    unsigned long long lmask = (1ull << lane) - 1ull;
    for (int c = 0; c < N / 256; ++c) {
        float4 v = row4[c * 64 + lane];
        float vv[4] = {v.x, v.y, v.z, v.w};
        #pragma unroll
        for (int s = 0; s < 4; ++s) {
            unsigned long long m = __ballot(vv[s] != 0.f);
            if (vv[s] != 0.f) {
                int idx = cnt + __popcll(m & lmask);
                if (idx < CAP) cols[idx] = c * 256 + lane * 4 + s;
            }
            cnt += __popcll(m);
        }
    }
    if (lane == 0) row_cnt[i] = cnt < CAP ? cnt : CAP;
}

// ---------------- fp32 -> bf16 convert (vectorized) ----------------
__global__ void f2bf_vec(const float* __restrict__ in, unsigned short* __restrict__ out, int n4) {
    int i = blockIdx.x * 256 + threadIdx.x;
    if (i >= n4) return;
    float4 v = ((const float4*)in)[i];
    ushort4 o;
    o.x = f2b(v.x); o.y = f2b(v.y); o.z = f2b(v.z); o.w = f2b(v.w);
    ((ushort4*)out)[i] = o;
}

// Wd1 [512][144] -> bf16 padded [512][160]
__global__ void convert_wd1(const float* __restrict__ in, unsigned short* __restrict__ out) {
    int idx = blockIdx.x * 256 + threadIdx.x;
    if (idx >= H1 * KD_PAD) return;
    int n = idx / KD_PAD, k = idx - n * KD_PAD;
    out[idx] = f2b(k < CIN_D ? in[n * CIN_D + k] : 0.f);
}

// ---------------- bf16 MFMA GEMM: C[M,Nc] = A[M,K] @ B[Nc,K]^T + bias ----------------
// Block tile: (FM*32) x 128, 4 waves as 2x2, wave tile (FM*16) x 64.
// LDS pitch 40 bf16 (80B): frag ds_read_b128 and staging ds_write_b128 are <=2-way bank aliased.
#define LDP 40
template<int FM>
__global__ __launch_bounds__(256) void gemm_mfma(const unsigned short* __restrict__ A,
                                                 const unsigned short* __restrict__ B,
                                                 const float* __restrict__ bias,
                                                 float* __restrict__ Cmat,
                                                 int M, int Nc, int K) {
    constexpr int BMT = FM * 32;
    __shared__ short As[BMT * LDP];
    __shared__ short Bs[128 * LDP];
    int bn = blockIdx.x, bm = blockIdx.y;
    int t = threadIdx.x;
    int lane = t & 63, wid = t >> 6;
    int wr = wid >> 1, wc = wid & 1;
    f32x4 acc[FM][4] = {};
    const short* Ag = (const short*)A + (size_t)(bm * BMT) * K;
    const short* Bg = (const short*)B + (size_t)(bn * 128) * K;
    int r0 = t >> 2, q0 = t & 3;   // chunk: row r0, 8-elem group q0
    int rbase = (lane & 15);
    int koff = (lane >> 4) * 8;

    for (int k0 = 0; k0 < K; k0 += 32) {
        // global -> regs
        short8 a0 = *(const short8*)(Ag + (size_t)r0 * K + k0 + q0 * 8);
        short8 a1;
        if constexpr (FM == 4) a1 = *(const short8*)(Ag + (size_t)(r0 + 64) * K + k0 + q0 * 8);
        short8 b0 = *(const short8*)(Bg + (size_t)r0 * K + k0 + q0 * 8);
        short8 b1 = *(const short8*)(Bg + (size_t)(r0 + 64) * K + k0 + q0 * 8);
        __syncthreads();   // previous iter's LDS reads complete
        *(short8*)(As + r0 * LDP + q0 * 8) = a0;
        if constexpr (FM == 4) *(short8*)(As + (r0 + 64) * LDP + q0 * 8) = a1;
        *(short8*)(Bs + r0 * LDP + q0 * 8) = b0;
        *(short8*)(Bs + (r0 + 64) * LDP + q0 * 8) = b1;
        __syncthreads();
        // fragments + MFMA
        bf16x8 af[FM], bfr[4];
        #pragma unroll
        for (int m = 0; m < FM; ++m)
            af[m] = *(const bf16x8*)(As + (wr * FM * 16 + m * 16 + rbase) * LDP + koff);
        #pragma unroll
        for (int n = 0; n < 4; ++n)
            bfr[n] = *(const bf16x8*)(Bs + (wc * 64 + n * 16 + rbase) * LDP + koff);
        #pragma unroll
        for (int m = 0; m < FM; ++m)
            #pragma unroll
            for (int n = 0; n < 4; ++n)
                acc[m][n] = __builtin_amdgcn_mfma_f32_16x16x32_bf16(af[m], bfr[n], acc[m][n], 0, 0, 0);
    }
    // epilogue: D layout col = lane&15, row = (lane>>4)*4 + reg  [m89-verified]
    int colb = bn * 128 + wc * 64;
    int rowb = bm * BMT + wr * FM * 16;
    #pragma unroll
    for (int m = 0; m < FM; ++m) {
        #pragma unroll
        for (int n = 0; n < 4; ++n) {
            int col = colb + n * 16 + (lane & 15);
            int row0 = rowb + m * 16 + (lane >> 4) * 4;
            float bs = bias[col];
            #pragma unroll
            for (int r = 0; r < 4; ++r)
                Cmat[(size_t)(row0 + r) * Nc + col] = acc[m][n][r] + bs;
        }
    }
}

// ---------------- per-head attention dot products hv0/hv1 ----------------
__global__ void head_dots(const float* __restrict__ Hlin, const float* __restrict__ v0,
                          const float* __restrict__ v1, float* __restrict__ hv0,
                          float* __restrict__ hv1) {
    int i = blockIdx.x;
    int lane = threadIdx.x;  // 64
    #pragma unroll
    for (int h = 0; h < HEADS; ++h) {
        float v = Hlin[(size_t)i * H1 + h * CH + lane];
        float p0 = v * v0[h * CH + lane];
        float p1 = v * v1[h * CH + lane];
        #pragma unroll
        for (int m = 32; m; m >>= 1) {
            p0 += __shfl_xor(p0, m);
            p1 += __shfl_xor(p1, m);
        }
        if (lane == 0) {
            hv0[i * HEADS + h] = p0;
            hv1[i * HEADS + h] = p1;
        }
    }
}

// ---------------- sparse GAT aggregation + elu -> bf16 ----------------
__global__ void attn_agg(const float* __restrict__ Hlin, const float* __restrict__ hv0,
                         const float* __restrict__ hv1, const int* __restrict__ col_idx,
                         const int* __restrict__ row_cnt, unsigned short* __restrict__ out) {
    int i = blockIdx.x;
    int tid = threadIdx.x;   // 512 threads: head = tid/64
    int h = tid >> 6;
    float a0 = hv0[i * HEADS + h];
    int cnt = row_cnt[i];
    const int* cols = col_idx + (size_t)i * CAP;
    float den = 0.f, acc = 0.f;
    for (int e = 0; e < cnt; ++e) {
        int j = cols[e];
        float x = a0 + hv1[j * HEADS + h];
        float sg = 1.f / (1.f + expf(-x)) - 0.5f;
        float w = expf(sg);
        den += w;
        acc += w * Hlin[(size_t)j * H1 + tid];
    }
    den = (den == 0.f) ? 1.f : den;
    float o = acc / den;
    out[(size_t)i * H1 + tid] = f2b((o > 0.f) ? o : expm1f(o));
}

// ---------------- per-node: beta softmax, alpha, Xd_bf (padded) ----------------
__global__ void pernode(const float* __restrict__ Z, const float* __restrict__ emb_table,
                        const int* __restrict__ slab, const float* __restrict__ Wb,
                        const float* __restrict__ bb, const float* __restrict__ Wa,
                        const float* __restrict__ ba, float* __restrict__ beta,
                        float* __restrict__ alpha, unsigned short* __restrict__ Xdb) {
    int i = blockIdx.x;
    int lane = threadIdx.x;  // 64
    __shared__ float sZ[H2];
    __shared__ float sE[EMB];
    __shared__ float sLog[C];
    sZ[lane] = Z[(size_t)i * H2 + lane];
    sZ[64 + lane] = Z[(size_t)i * H2 + 64 + lane];
    int s = slab[i];
    if (lane < EMB) sE[lane] = emb_table[s * EMB + lane];
    __syncthreads();
    // Xd bf16 padded [N][160]
    Xdb[(size_t)i * KD_PAD + lane] = f2b(sZ[lane]);
    Xdb[(size_t)i * KD_PAD + 64 + lane] = f2b(sZ[64 + lane]);
    if (lane < EMB) Xdb[(size_t)i * KD_PAD + H2 + lane] = f2b(sE[lane]);
    if (lane < KD_PAD - CIN_D) Xdb[(size_t)i * KD_PAD + CIN_D + lane] = 0;
    // beta logits over elu(Z)
    if (lane < C) {
        float acc = bb[lane];
        for (int k = 0; k < H2; ++k) {
            float z = sZ[k];
            float e = z > 0.f ? z : expm1f(z);
            acc += e * Wb[lane * H2 + k];
        }
        sLog[lane] = acc;
    }
    __syncthreads();
    if (lane == 0) {
        float mx = sLog[0];
        for (int c = 1; c < C; ++c) mx = fmaxf(mx, sLog[c]);
        float sm = 0.f;
        for (int c = 0; c < C; ++c) { float e = expf(sLog[c] - mx); sLog[c] = e; sm += e; }
        for (int c = 0; c < C; ++c) sLog[c] /= sm;
    }
    __syncthreads();
    if (lane < C) beta[(size_t)i * C + lane] = sLog[lane];
    // alpha = elu(concat(Z,emb)) . Wa + ba
    float x0 = sZ[lane];        x0 = x0 > 0.f ? x0 : expm1f(x0);
    float x1 = sZ[64 + lane];   x1 = x1 > 0.f ? x1 : expm1f(x1);
    float p = x0 * Wa[lane] + x1 * Wa[64 + lane];
    if (lane < EMB) {
        float x2 = sE[lane];    x2 = x2 > 0.f ? x2 : expm1f(x2);
        p += x2 * Wa[H2 + lane];
    }
    #pragma unroll
    for (int m = 32; m; m >>= 1) p += __shfl_xor(p, m);
    if (lane == 0) alpha[i] = p + ba[0];
}

// ---------------- per-(slice,gene) tables ----------------
__global__ void theta_tables(const float* __restrict__ logtheta, const float* __restrict__ gamma,
                             float* __restrict__ th_v, float* __restrict__ aux_sg,
                             float* __restrict__ egam) {
    int idx = blockIdx.x * 256 + threadIdx.x;
    if (idx >= S * G) return;
    float th = expf(logtheta[idx]);
    th_v[idx] = th;
    aux_sg[idx] = th * logf(th + EPSV) - lgammaf(th + EPSV);
    egam[idx] = expf(gamma[idx]);
}

// T1[k][sg] = lgamma(k+th+eps) - lgamma(th+eps) + th*log(th+eps)
__global__ void t1_table(const float* __restrict__ th_v, const float* __restrict__ aux_sg,
                         float* __restrict__ T1) {
    int idx = blockIdx.x * 256 + threadIdx.x;
    if (idx >= KMAX * S * G) return;
    int k = idx / (S * G), sg = idx - k * (S * G);
    T1[idx] = lgammaf((float)k + th_v[sg] + EPSV) + aux_sg[sg];
}

// ---------------- per-row NB loss + reconstruction sq-norm ----------------
__global__ void loss_row(const float* __restrict__ Xr, const float* __restrict__ nf,
                         const float* __restrict__ cm, const float* __restrict__ beta,
                         const float* __restrict__ basis, const float* __restrict__ alpha,
                         const float* __restrict__ lib, const int* __restrict__ slab,
                         const float* __restrict__ gamma, const float* __restrict__ th_v,
                         const float* __restrict__ egam, const float* __restrict__ T1,
                         float* __restrict__ ll_row, float* __restrict__ sq_row) {
    int i = blockIdx.x;
    int t = threadIdx.x;  // 256
    __shared__ float sb[C];
    if (t < C) sb[t] = beta[(size_t)i * C + t];
    __syncthreads();
    int s = slab[i];
    float A = alpha[i], L = lib[i];
    float muf = L * expf(A);       // mu = muf * (bd+eps) * egam[sg]
    float logL = logf(L);
    float all = 0.f, asq = 0.f;
    for (int g = t; g < G; g += 256) {
        int sg = s * G + g;
        float bd = 0.f;
        #pragma unroll
        for (int c = 0; c < C; ++c) bd += sb[c] * basis[c * G + g];
        float ebd = bd + EPSV;
        float lbd = logf(ebd);
        float mu = muf * ebd * egam[sg];
        float th = th_v[sg];
        float k = cm[(size_t)i * G + g];
        int ki = (int)(k + 0.5f);
        float ll = T1[ki * (S * G) + sg] - (th + k) * logf(th + mu + EPSV)
                 + k * (logL + lbd + A + gamma[sg]);
        all += ll;
        float d = nf[(size_t)i * G + g] - Xr[(size_t)i * G + g];
        asq += d * d;
    }
    __shared__ float r1[256], r2[256];
    r1[t] = all; r2[t] = asq;
    __syncthreads();
    for (int o = 128; o; o >>= 1) {
        if (t < o) { r1[t] += r1[t + o]; r2[t] += r2[t + o]; }
        __syncthreads();
    }
    if (t == 0) { ll_row[i] = r1[0]; sq_row[i] = r2[0]; }
}

// ---------------- final scalar ----------------
__global__ void finalize(const float* __restrict__ ll_row, const float* __restrict__ sq_row,
                         float* __restrict__ out) {
    int t = threadIdx.x;  // 256
    float a = 0.f, b = 0.f;
    for (int r = t; r < N; r += 256) {
        a += ll_row[r];
        b += sqrtf(sq_row[r]);
    }
    __shared__ float r1[256], r2[256];
    r1[t] = a; r2[t] = b;
    __syncthreads();
    for (int o = 128; o; o >>= 1) {
        if (t < o) { r1[t] += r1[t + o]; r2[t] += r2[t + o]; }
        __syncthreads();
    }
    if (t == 0) out[0] = -(r1[0] / (float)N) + 0.1f * (r2[0] / (float)N);
}

extern "C" void kernel_launch(void* const* d_in, const int* in_sizes, int n_in,
                              void* d_out, int out_size, void* d_ws, size_t ws_size,
                              hipStream_t stream) {
    const float* adj       = (const float*)d_in[0];
    const float* node_f    = (const float*)d_in[1];
    const float* count_m   = (const float*)d_in[2];
    const float* lib       = (const float*)d_in[3];
    const int*   slab      = (const int*)d_in[4];
    const float* basis     = (const float*)d_in[5];
    const float* We1       = (const float*)d_in[6];
    const float* be1       = (const float*)d_in[7];
    const float* v0e1      = (const float*)d_in[8];
    const float* v1e1      = (const float*)d_in[9];
    const float* W2        = (const float*)d_in[10];
    const float* b2        = (const float*)d_in[11];
    const float* Wd1       = (const float*)d_in[12];
    const float* bd1       = (const float*)d_in[13];
    const float* v0d1      = (const float*)d_in[14];
    const float* v1d1      = (const float*)d_in[15];
    const float* Wd2       = (const float*)d_in[16];
    const float* bd2       = (const float*)d_in[17];
    const float* Wa        = (const float*)d_in[18];
    const float* ba        = (const float*)d_in[19];
    const float* Wb        = (const float*)d_in[20];
    const float* bb        = (const float*)d_in[21];
    const float* gamma     = (const float*)d_in[22];
    const float* logtheta  = (const float*)d_in[23];
    const float* emb_table = (const float*)d_in[24];
    float* out = (float*)d_out;

    char* w = (char*)d_ws;
    auto alloc = [&](size_t bytes) { void* p = (void*)w; w += (bytes + 255) & ~(size_t)255; return p; };
    int*   col_idx = (int*)  alloc((size_t)N * CAP * 4);
    int*   row_cnt = (int*)  alloc((size_t)N * 4);
    float* bufA    = (float*)alloc((size_t)N * H1 * 4);      // Hlin (enc, then dec)
    unsigned short* Hgat_bf = (unsigned short*)alloc((size_t)N * H1 * 2);
    float* Z       = (float*)alloc((size_t)N * H2 * 4);
    unsigned short* Xd_bf   = (unsigned short*)alloc((size_t)N * KD_PAD * 2);
    float* beta    = (float*)alloc((size_t)N * C * 4);
    float* alpha   = (float*)alloc((size_t)N * 4);
    float* hv0     = (float*)alloc((size_t)N * HEADS * 4);
    float* hv1     = (float*)alloc((size_t)N * HEADS * 4);
    float* th_v    = (float*)alloc((size_t)S * G * 4);
    float* aux_sg  = (float*)alloc((size_t)S * G * 4);
    float* egam    = (float*)alloc((size_t)S * G * 4);
    float* T1      = (float*)alloc((size_t)KMAX * S * G * 4);
    float* Xrec    = (float*)alloc((size_t)N * G * 4);
    float* ll_row  = (float*)alloc((size_t)N * 4);
    float* sq_row  = (float*)alloc((size_t)N * 4);
    unsigned short* nf_bf  = (unsigned short*)alloc((size_t)N * G * 2);
    unsigned short* We1_bf = (unsigned short*)alloc((size_t)H1 * G * 2);
    unsigned short* W2_bf  = (unsigned short*)alloc((size_t)H2 * H1 * 2);
    unsigned short* Wd1_bf = (unsigned short*)alloc((size_t)H1 * KD_PAD * 2);
    unsigned short* Wd2_bf = (unsigned short*)alloc((size_t)G * H1 * 2);

    // tables + conversions
    hipLaunchKernelGGL(build_csr, dim3(N), dim3(64), 0, stream, adj, col_idx, row_cnt);
    hipLaunchKernelGGL(theta_tables, dim3((S * G + 255) / 256), dim3(256), 0, stream,
                       logtheta, gamma, th_v, aux_sg, egam);
    hipLaunchKernelGGL(t1_table, dim3((KMAX * S * G + 255) / 256), dim3(256), 0, stream,
                       th_v, aux_sg, T1);
    hipLaunchKernelGGL(f2bf_vec, dim3((N * G / 4 + 255) / 256), dim3(256), 0, stream,
                       node_f, nf_bf, N * G / 4);
    hipLaunchKernelGGL(f2bf_vec, dim3((H1 * G / 4 + 255) / 256), dim3(256), 0, stream,
                       We1, We1_bf, H1 * G / 4);
    hipLaunchKernelGGL(f2bf_vec, dim3((H2 * H1 / 4 + 255) / 256), dim3(256), 0, stream,
                       W2, W2_bf, H2 * H1 / 4);
    hipLaunchKernelGGL(convert_wd1, dim3((H1 * KD_PAD + 255) / 256), dim3(256), 0, stream,
                       Wd1, Wd1_bf);
    hipLaunchKernelGGL(f2bf_vec, dim3((G * H1 / 4 + 255) / 256), dim3(256), 0, stream,
                       Wd2, Wd2_bf, G * H1 / 4);

    // 1. encoder linear: Hlin = nf @ We1^T + be1   [4096,512], K=2048
    hipLaunchKernelGGL(HIP_KERNEL_NAME(gemm_mfma<2>), dim3(H1 / 128, N / 64), dim3(256), 0, stream,
                       nf_bf, We1_bf, be1, bufA, N, H1, G);
    // 2-3. encoder attention
    hipLaunchKernelGGL(head_dots, dim3(N), dim3(64), 0, stream, bufA, v0e1, v1e1, hv0, hv1);
    hipLaunchKernelGGL(attn_agg, dim3(N), dim3(H1), 0, stream,
                       bufA, hv0, hv1, col_idx, row_cnt, Hgat_bf);
    // 4. Z = Hgat @ W2^T + b2   [4096,128], K=512
    hipLaunchKernelGGL(HIP_KERNEL_NAME(gemm_mfma<2>), dim3(H2 / 128, N / 64), dim3(256), 0, stream,
                       Hgat_bf, W2_bf, b2, Z, N, H2, H1);
    // 5. per-node beta/alpha/Xd
    hipLaunchKernelGGL(pernode, dim3(N), dim3(64), 0, stream,
                       Z, emb_table, slab, Wb, bb, Wa, ba, beta, alpha, Xd_bf);
    // 6. decoder linear: Hd = Xd @ Wd1^T + bd1   [4096,512], K=160(pad)
    hipLaunchKernelGGL(HIP_KERNEL_NAME(gemm_mfma<2>), dim3(H1 / 128, N / 64), dim3(256), 0, stream,
                       Xd_bf, Wd1_bf, bd1, bufA, N, H1, KD_PAD);
    // 7-8. decoder attention
    hipLaunchKernelGGL(head_dots, dim3(N), dim3(64), 0, stream, bufA, v0d1, v1d1, hv0, hv1);
    hipLaunchKernelGGL(attn_agg, dim3(N), dim3(H1), 0, stream,
                       bufA, hv0, hv1, col_idx, row_cnt, Hgat_bf);
    // 9. X_recon = Hd_act @ Wd2^T + bd2   [4096,2048], K=512
    hipLaunchKernelGGL(HIP_KERNEL_NAME(gemm_mfma<4>), dim3(G / 128, N / 128), dim3(256), 0, stream,
                       Hgat_bf, Wd2_bf, bd2, Xrec, N, G, H1);
    // 10-11. loss
    hipLaunchKernelGGL(loss_row, dim3(N), dim3(256), 0, stream,
                       Xrec, node_f, count_m, beta, basis, alpha, lib, slab, gamma,
                       th_v, egam, T1, ll_row, sq_row);
    hipLaunchKernelGGL(finalize, dim3(1), dim3(256), 0, stream, ll_row, sq_row, out);
}

// Round 4
// 273.149 us; speedup vs baseline: 2.3430x; 1.2409x over previous
//
#include <hip/hip_runtime.h>
#include <hip/hip_bf16.h>
#include <math.h>

#define N 4096
#define G 2048
#define H1 512
#define H2 128
#define HEADS 8
#define EMB 16
#define C 20
#define S 4
#define CH 64
#define CIN_D (H2 + EMB)   // 144
#define KD_PAD 160         // CIN_D padded to multiple of 32
#define KB_PAD 32          // C padded to 32
#define CAP 128
#define EPSV 1e-6f
#define KMAX 50

typedef __attribute__((ext_vector_type(8))) short short8;
typedef __attribute__((ext_vector_type(8))) short bf16x8;
typedef __attribute__((ext_vector_type(4))) float f32x4;

__device__ __forceinline__ unsigned short f2b(float x) {
    __hip_bfloat16 h = __float2bfloat16(x);
    return *reinterpret_cast<unsigned short*>(&h);
}

// ---------------- CSR build from dense binary adjacency ----------------
__global__ void build_csr(const float* __restrict__ adj, int* __restrict__ col_idx,
                          int* __restrict__ row_cnt) {
    int i = blockIdx.x;
    int lane = threadIdx.x;  // 64
    int cnt = 0;
    const float4* row4 = (const float4*)(adj + (size_t)i * N);
    int* cols = col_idx + (size_t)i * CAP;
    unsigned long long lmask = (1ull << lane) - 1ull;
    for (int c = 0; c < N / 256; ++c) {
        float4 v = row4[c * 64 + lane];
        float vv[4] = {v.x, v.y, v.z, v.w};
        #pragma unroll
        for (int s = 0; s < 4; ++s) {
            unsigned long long m = __ballot(vv[s] != 0.f);
            if (vv[s] != 0.f) {
                int idx = cnt + __popcll(m & lmask);
                if (idx < CAP) cols[idx] = c * 256 + lane * 4 + s;
            }
            cnt += __popcll(m);
        }
    }
    if (lane == 0) row_cnt[i] = cnt < CAP ? cnt : CAP;
}

// ---------------- fp32 -> bf16 convert (vectorized) ----------------
__global__ void f2bf_vec(const float* __restrict__ in, unsigned short* __restrict__ out, int n4) {
    int i = blockIdx.x * 256 + threadIdx.x;
    if (i >= n4) return;
    float4 v = ((const float4*)in)[i];
    ushort4 o;
    o.x = f2b(v.x); o.y = f2b(v.y); o.z = f2b(v.z); o.w = f2b(v.w);
    ((ushort4*)out)[i] = o;
}

// Wd1 [512][144] -> bf16 padded [512][160]
__global__ void convert_wd1(const float* __restrict__ in, unsigned short* __restrict__ out) {
    int idx = blockIdx.x * 256 + threadIdx.x;
    if (idx >= H1 * KD_PAD) return;
    int n = idx / KD_PAD, k = idx - n * KD_PAD;
    out[idx] = f2b(k < CIN_D ? in[n * CIN_D + k] : 0.f);
}

// basis [20][2048] -> basisT bf16 [2048][32] (K-padded)
__global__ void convert_basisT(const float* __restrict__ basis, unsigned short* __restrict__ out) {
    int idx = blockIdx.x * 256 + threadIdx.x;
    if (idx >= G * KB_PAD) return;
    int g = idx >> 5, c = idx & 31;
    out[idx] = f2b(c < C ? basis[c * G + g] : 0.f);
}

// ---------------- bf16 MFMA GEMM: C[M,Nc] = A[M,K] @ B[Nc,K]^T + bias ----------------
#define LDP 40
template<int FM>
__global__ __launch_bounds__(256) void gemm_mfma(const unsigned short* __restrict__ A,
                                                 const unsigned short* __restrict__ B,
                                                 const float* __restrict__ bias,
                                                 float* __restrict__ Cmat,
                                                 int M, int Nc, int K) {
    constexpr int BMT = FM * 32;
    __shared__ short As[BMT * LDP];
    __shared__ short Bs[128 * LDP];
    int bn = blockIdx.x, bm = blockIdx.y;
    int t = threadIdx.x;
    int lane = t & 63, wid = t >> 6;
    int wr = wid >> 1, wc = wid & 1;
    f32x4 acc[FM][4] = {};
    const short* Ag = (const short*)A + (size_t)(bm * BMT) * K;
    const short* Bg = (const short*)B + (size_t)(bn * 128) * K;
    int r0 = t >> 2, q0 = t & 3;
    int rbase = (lane & 15);
    int koff = (lane >> 4) * 8;

    for (int k0 = 0; k0 < K; k0 += 32) {
        short8 a0 = *(const short8*)(Ag + (size_t)r0 * K + k0 + q0 * 8);
        short8 a1;
        if constexpr (FM == 4) a1 = *(const short8*)(Ag + (size_t)(r0 + 64) * K + k0 + q0 * 8);
        short8 b0 = *(const short8*)(Bg + (size_t)r0 * K + k0 + q0 * 8);
        short8 b1 = *(const short8*)(Bg + (size_t)(r0 + 64) * K + k0 + q0 * 8);
        __syncthreads();
        *(short8*)(As + r0 * LDP + q0 * 8) = a0;
        if constexpr (FM == 4) *(short8*)(As + (r0 + 64) * LDP + q0 * 8) = a1;
        *(short8*)(Bs + r0 * LDP + q0 * 8) = b0;
        *(short8*)(Bs + (r0 + 64) * LDP + q0 * 8) = b1;
        __syncthreads();
        bf16x8 af[FM], bfr[4];
        #pragma unroll
        for (int m = 0; m < FM; ++m)
            af[m] = *(const bf16x8*)(As + (wr * FM * 16 + m * 16 + rbase) * LDP + koff);
        #pragma unroll
        for (int n = 0; n < 4; ++n)
            bfr[n] = *(const bf16x8*)(Bs + (wc * 64 + n * 16 + rbase) * LDP + koff);
        #pragma unroll
        for (int m = 0; m < FM; ++m)
            #pragma unroll
            for (int n = 0; n < 4; ++n)
                acc[m][n] = __builtin_amdgcn_mfma_f32_16x16x32_bf16(af[m], bfr[n], acc[m][n], 0, 0, 0);
    }
    int colb = bn * 128 + wc * 64;
    int rowb = bm * BMT + wr * FM * 16;
    #pragma unroll
    for (int m = 0; m < FM; ++m) {
        #pragma unroll
        for (int n = 0; n < 4; ++n) {
            int col = colb + n * 16 + (lane & 15);
            int row0 = rowb + m * 16 + (lane >> 4) * 4;
            float bs = bias[col];
            #pragma unroll
            for (int r = 0; r < 4; ++r)
                Cmat[(size_t)(row0 + r) * Nc + col] = acc[m][n][r] + bs;
        }
    }
}

// ---------------- fused reconstruction GEMM + (nf - Xr)^2 row-reduce ----------------
// C would be [N,G] = Hgat@Wd2^T + bd2; never materialized. sq_part[N][16] written instead.
__global__ __launch_bounds__(256) void gemm_recon_sq(const unsigned short* __restrict__ A,
                                                     const unsigned short* __restrict__ B,
                                                     const float* __restrict__ bias,
                                                     const float* __restrict__ nf,
                                                     float* __restrict__ sq_part) {
    constexpr int K = H1;
    __shared__ short As[128 * LDP];
    __shared__ short Bs[128 * LDP];
    __shared__ float red[4][64];
    int bn = blockIdx.x, bm = blockIdx.y;
    int t = threadIdx.x;
    int lane = t & 63, wid = t >> 6;
    int wr = wid >> 1, wc = wid & 1;
    f32x4 acc[4][4] = {};
    const short* Ag = (const short*)A + (size_t)(bm * 128) * K;
    const short* Bg = (const short*)B + (size_t)(bn * 128) * K;
    int r0 = t >> 2, q0 = t & 3;
    int rbase = (lane & 15);
    int koff = (lane >> 4) * 8;

    for (int k0 = 0; k0 < K; k0 += 32) {
        short8 a0 = *(const short8*)(Ag + (size_t)r0 * K + k0 + q0 * 8);
        short8 a1 = *(const short8*)(Ag + (size_t)(r0 + 64) * K + k0 + q0 * 8);
        short8 b0 = *(const short8*)(Bg + (size_t)r0 * K + k0 + q0 * 8);
        short8 b1 = *(const short8*)(Bg + (size_t)(r0 + 64) * K + k0 + q0 * 8);
        __syncthreads();
        *(short8*)(As + r0 * LDP + q0 * 8) = a0;
        *(short8*)(As + (r0 + 64) * LDP + q0 * 8) = a1;
        *(short8*)(Bs + r0 * LDP + q0 * 8) = b0;
        *(short8*)(Bs + (r0 + 64) * LDP + q0 * 8) = b1;
        __syncthreads();
        bf16x8 af[4], bfr[4];
        #pragma unroll
        for (int m = 0; m < 4; ++m)
            af[m] = *(const bf16x8*)(As + (wr * 64 + m * 16 + rbase) * LDP + koff);
        #pragma unroll
        for (int n = 0; n < 4; ++n)
            bfr[n] = *(const bf16x8*)(Bs + (wc * 64 + n * 16 + rbase) * LDP + koff);
        #pragma unroll
        for (int m = 0; m < 4; ++m)
            #pragma unroll
            for (int n = 0; n < 4; ++n)
                acc[m][n] = __builtin_amdgcn_mfma_f32_16x16x32_bf16(af[m], bfr[n], acc[m][n], 0, 0, 0);
    }
    int colb = bn * 128 + wc * 64;
    int rowb = bm * 128 + wr * 64;
    float part[4][4];
    #pragma unroll
    for (int m = 0; m < 4; ++m) {
        #pragma unroll
        for (int r = 0; r < 4; ++r) part[m][r] = 0.f;
        #pragma unroll
        for (int n = 0; n < 4; ++n) {
            int col = colb + n * 16 + (lane & 15);
            float bs = bias[col];
            int row0 = rowb + m * 16 + (lane >> 4) * 4;
            #pragma unroll
            for (int r = 0; r < 4; ++r) {
                float d = nf[(size_t)(row0 + r) * G + col] - (acc[m][n][r] + bs);
                part[m][r] += d * d;
            }
        }
    }
    #pragma unroll
    for (int m = 0; m < 4; ++m)
        #pragma unroll
        for (int r = 0; r < 4; ++r) {
            float v = part[m][r];
            v += __shfl_xor(v, 1); v += __shfl_xor(v, 2);
            v += __shfl_xor(v, 4); v += __shfl_xor(v, 8);
            part[m][r] = v;
        }
    if ((lane & 15) == 0) {
        int q = lane >> 4;
        #pragma unroll
        for (int m = 0; m < 4; ++m)
            #pragma unroll
            for (int r = 0; r < 4; ++r)
                red[wid][m * 16 + q * 4 + r] = part[m][r];
    }
    __syncthreads();
    if (t < 128) {
        int wr2 = t >> 6, loc = t & 63;
        float v = red[wr2 * 2 + 0][loc] + red[wr2 * 2 + 1][loc];
        sq_part[(size_t)(bm * 128 + t) * 16 + bn] = v;
    }
}

// ---------------- fused beta@basis GEMM + NB log-likelihood row-reduce ----------------
__global__ __launch_bounds__(256) void bd_ll(const unsigned short* __restrict__ A,   // beta_bf [N][32]
                                             const unsigned short* __restrict__ B,   // basisT [G][32]
                                             const float* __restrict__ cm,
                                             const int* __restrict__ slab,
                                             const float* __restrict__ muf,
                                             const float* __restrict__ kco,
                                             const float* __restrict__ th_v,
                                             const float* __restrict__ egam,
                                             const float* __restrict__ gam,
                                             const float* __restrict__ T1,
                                             float* __restrict__ ll_part) {
    constexpr int K = KB_PAD;
    __shared__ short As[128 * LDP];
    __shared__ short Bs[128 * LDP];
    __shared__ float red[4][64];
    int bn = blockIdx.x, bm = blockIdx.y;
    int t = threadIdx.x;
    int lane = t & 63, wid = t >> 6;
    int wr = wid >> 1, wc = wid & 1;
    f32x4 acc[4][4] = {};
    const short* Ag = (const short*)A + (size_t)(bm * 128) * K;
    const short* Bg = (const short*)B + (size_t)(bn * 128) * K;
    int r0 = t >> 2, q0 = t & 3;
    int rbase = (lane & 15);
    int koff = (lane >> 4) * 8;
    {
        short8 a0 = *(const short8*)(Ag + (size_t)r0 * K + q0 * 8);
        short8 a1 = *(const short8*)(Ag + (size_t)(r0 + 64) * K + q0 * 8);
        short8 b0 = *(const short8*)(Bg + (size_t)r0 * K + q0 * 8);
        short8 b1 = *(const short8*)(Bg + (size_t)(r0 + 64) * K + q0 * 8);
        *(short8*)(As + r0 * LDP + q0 * 8) = a0;
        *(short8*)(As + (r0 + 64) * LDP + q0 * 8) = a1;
        *(short8*)(Bs + r0 * LDP + q0 * 8) = b0;
        *(short8*)(Bs + (r0 + 64) * LDP + q0 * 8) = b1;
        __syncthreads();
        bf16x8 af[4], bfr[4];
        #pragma unroll
        for (int m = 0; m < 4; ++m)
            af[m] = *(const bf16x8*)(As + (wr * 64 + m * 16 + rbase) * LDP + koff);
        #pragma unroll
        for (int n = 0; n < 4; ++n)
            bfr[n] = *(const bf16x8*)(Bs + (wc * 64 + n * 16 + rbase) * LDP + koff);
        #pragma unroll
        for (int m = 0; m < 4; ++m)
            #pragma unroll
            for (int n = 0; n < 4; ++n)
                acc[m][n] = __builtin_amdgcn_mfma_f32_16x16x32_bf16(af[m], bfr[n], acc[m][n], 0, 0, 0);
    }
    int colb = bn * 128 + wc * 64;
    int rowb = bm * 128 + wr * 64;
    float part[4][4];
    #pragma unroll
    for (int m = 0; m < 4; ++m) {
        int rq = rowb + m * 16 + (lane >> 4) * 4;
        #pragma unroll
        for (int r = 0; r < 4; ++r) {
            int row = rq + r;
            int sgb = slab[row] * G;
            float mufv = muf[row], kcov = kco[row];
            float p = 0.f;
            #pragma unroll
            for (int n = 0; n < 4; ++n) {
                int col = colb + n * 16 + (lane & 15);
                int sg = sgb + col;
                float ebd = acc[m][n][r] + EPSV;       // bd >= 0
                float lbd = __logf(ebd);
                float mu = mufv * ebd * egam[sg];
                float th = th_v[sg];
                float k = cm[(size_t)row * G + col];
                int ki = (int)(k + 0.5f);
                p += T1[sg * KMAX + ki] - (th + k) * __logf(th + mu + EPSV)
                   + k * (kcov + lbd + gam[sg]);
            }
            part[m][r] = p;
        }
    }
    #pragma unroll
    for (int m = 0; m < 4; ++m)
        #pragma unroll
        for (int r = 0; r < 4; ++r) {
            float v = part[m][r];
            v += __shfl_xor(v, 1); v += __shfl_xor(v, 2);
            v += __shfl_xor(v, 4); v += __shfl_xor(v, 8);
            part[m][r] = v;
        }
    if ((lane & 15) == 0) {
        int q = lane >> 4;
        #pragma unroll
        for (int m = 0; m < 4; ++m)
            #pragma unroll
            for (int r = 0; r < 4; ++r)
                red[wid][m * 16 + q * 4 + r] = part[m][r];
    }
    __syncthreads();
    if (t < 128) {
        int wr2 = t >> 6, loc = t & 63;
        float v = red[wr2 * 2 + 0][loc] + red[wr2 * 2 + 1][loc];
        ll_part[(size_t)(bm * 128 + t) * 16 + bn] = v;
    }
}

// ---------------- per-head attention dot products ----------------
__global__ void head_dots(const float* __restrict__ Hlin, const float* __restrict__ v0,
                          const float* __restrict__ v1, float* __restrict__ hv0,
                          float* __restrict__ hv1) {
    int i = blockIdx.x;
    int lane = threadIdx.x;  // 64
    #pragma unroll
    for (int h = 0; h < HEADS; ++h) {
        float v = Hlin[(size_t)i * H1 + h * CH + lane];
        float p0 = v * v0[h * CH + lane];
        float p1 = v * v1[h * CH + lane];
        #pragma unroll
        for (int m = 32; m; m >>= 1) {
            p0 += __shfl_xor(p0, m);
            p1 += __shfl_xor(p1, m);
        }
        if (lane == 0) {
            hv0[i * HEADS + h] = p0;
            hv1[i * HEADS + h] = p1;
        }
    }
}

// ---------------- sparse GAT aggregation + elu -> bf16 ----------------
__global__ void attn_agg(const float* __restrict__ Hlin, const float* __restrict__ hv0,
                         const float* __restrict__ hv1, const int* __restrict__ col_idx,
                         const int* __restrict__ row_cnt, unsigned short* __restrict__ out) {
    int i = blockIdx.x;
    int tid = threadIdx.x;   // 512
    int h = tid >> 6;
    float a0 = hv0[i * HEADS + h];
    int cnt = row_cnt[i];
    const int* cols = col_idx + (size_t)i * CAP;
    float den = 0.f, acc = 0.f;
    for (int e = 0; e < cnt; ++e) {
        int j = cols[e];
        float x = a0 + hv1[j * HEADS + h];
        float sg = 1.f / (1.f + __expf(-x)) - 0.5f;
        float w = __expf(sg);
        den += w;
        acc += w * Hlin[(size_t)j * H1 + tid];
    }
    den = (den == 0.f) ? 1.f : den;
    float o = acc / den;
    out[(size_t)i * H1 + tid] = f2b((o > 0.f) ? o : expm1f(o));
}

// ---------------- per-node: beta_bf, muf/kco, Xd_bf ----------------
__global__ void pernode(const float* __restrict__ Z, const float* __restrict__ emb_table,
                        const int* __restrict__ slab, const float* __restrict__ Wb,
                        const float* __restrict__ bb, const float* __restrict__ Wa,
                        const float* __restrict__ ba, const float* __restrict__ lib,
                        unsigned short* __restrict__ beta_bf, float* __restrict__ muf,
                        float* __restrict__ kco, unsigned short* __restrict__ Xdb) {
    int i = blockIdx.x;
    int lane = threadIdx.x;  // 64
    __shared__ float sZ[H2];
    __shared__ float sE[EMB];
    __shared__ float sLog[C];
    __shared__ float sAl;
    sZ[lane] = Z[(size_t)i * H2 + lane];
    sZ[64 + lane] = Z[(size_t)i * H2 + 64 + lane];
    int s = slab[i];
    if (lane < EMB) sE[lane] = emb_table[s * EMB + lane];
    __syncthreads();
    Xdb[(size_t)i * KD_PAD + lane] = f2b(sZ[lane]);
    Xdb[(size_t)i * KD_PAD + 64 + lane] = f2b(sZ[64 + lane]);
    if (lane < EMB) Xdb[(size_t)i * KD_PAD + H2 + lane] = f2b(sE[lane]);
    if (lane < KD_PAD - CIN_D) Xdb[(size_t)i * KD_PAD + CIN_D + lane] = 0;
    if (lane < C) {
        float acc = bb[lane];
        for (int k = 0; k < H2; ++k) {
            float z = sZ[k];
            float e = z > 0.f ? z : expm1f(z);
            acc += e * Wb[lane * H2 + k];
        }
        sLog[lane] = acc;
    }
    __syncthreads();
    if (lane == 0) {
        float mx = sLog[0];
        for (int c = 1; c < C; ++c) mx = fmaxf(mx, sLog[c]);
        float sm = 0.f;
        for (int c = 0; c < C; ++c) { float e = __expf(sLog[c] - mx); sLog[c] = e; sm += e; }
        for (int c = 0; c < C; ++c) sLog[c] /= sm;
    }
    __syncthreads();
    if (lane < KB_PAD) beta_bf[(size_t)i * KB_PAD + lane] = (lane < C) ? f2b(sLog[lane]) : 0;
    // alpha
    float x0 = sZ[lane];        x0 = x0 > 0.f ? x0 : expm1f(x0);
    float x1 = sZ[64 + lane];   x1 = x1 > 0.f ? x1 : expm1f(x1);
    float p = x0 * Wa[lane] + x1 * Wa[64 + lane];
    if (lane < EMB) {
        float x2 = sE[lane];    x2 = x2 > 0.f ? x2 : expm1f(x2);
        p += x2 * Wa[H2 + lane];
    }
    #pragma unroll
    for (int m = 32; m; m >>= 1) p += __shfl_xor(p, m);
    if (lane == 0) sAl = p + ba[0];
    __syncthreads();
    if (lane == 0) {
        float A = sAl, L = lib[i];
        muf[i] = L * __expf(A);
        kco[i] = __logf(L) + A;
    }
}

// ---------------- per-(slice,gene) tables ----------------
__global__ void theta_tables(const float* __restrict__ logtheta, const float* __restrict__ gamma,
                             float* __restrict__ th_v, float* __restrict__ aux_sg,
                             float* __restrict__ egam) {
    int idx = blockIdx.x * 256 + threadIdx.x;
    if (idx >= S * G) return;
    float th = __expf(logtheta[idx]);
    th_v[idx] = th;
    aux_sg[idx] = th * __logf(th + EPSV) - lgammaf(th + EPSV);
    egam[idx] = __expf(gamma[idx]);
}

// T1[sg*KMAX + k] = lgamma(k+th+eps) - lgamma(th+eps) + th*log(th+eps)
__global__ void t1_table(const float* __restrict__ th_v, const float* __restrict__ aux_sg,
                         float* __restrict__ T1) {
    int idx = blockIdx.x * 256 + threadIdx.x;
    if (idx >= KMAX * S * G) return;
    int sg = idx / KMAX, k = idx - sg * KMAX;
    T1[idx] = lgammaf((float)k + th_v[sg] + EPSV) + aux_sg[sg];
}

// ---------------- two-stage final reduce ----------------
__global__ void row_reduce(const float* __restrict__ ll_part, const float* __restrict__ sq_part,
                           float* __restrict__ part_ll, float* __restrict__ part_sq) {
    int blk = blockIdx.x, lane = threadIdx.x;  // 64 blocks x 64 lanes
    int row = blk * 64 + lane;
    float s1 = 0.f, s2 = 0.f;
    #pragma unroll
    for (int j = 0; j < 16; ++j) {
        s1 += ll_part[(size_t)row * 16 + j];
        s2 += sq_part[(size_t)row * 16 + j];
    }
    float b = sqrtf(s2);
    #pragma unroll
    for (int m = 32; m; m >>= 1) { s1 += __shfl_xor(s1, m); b += __shfl_xor(b, m); }
    if (lane == 0) { part_ll[blk] = s1; part_sq[blk] = b; }
}

__global__ void finalize2(const float* __restrict__ part_ll, const float* __restrict__ part_sq,
                          float* __restrict__ out) {
    int lane = threadIdx.x;  // 64
    float a = part_ll[lane], b = part_sq[lane];
    #pragma unroll
    for (int m = 32; m; m >>= 1) { a += __shfl_xor(a, m); b += __shfl_xor(b, m); }
    if (lane == 0) out[0] = -(a / (float)N) + 0.1f * (b / (float)N);
}

extern "C" void kernel_launch(void* const* d_in, const int* in_sizes, int n_in,
                              void* d_out, int out_size, void* d_ws, size_t ws_size,
                              hipStream_t stream) {
    const float* adj       = (const float*)d_in[0];
    const float* node_f    = (const float*)d_in[1];
    const float* count_m   = (const float*)d_in[2];
    const float* lib       = (const float*)d_in[3];
    const int*   slab      = (const int*)d_in[4];
    const float* basis     = (const float*)d_in[5];
    const float* We1       = (const float*)d_in[6];
    const float* be1       = (const float*)d_in[7];
    const float* v0e1      = (const float*)d_in[8];
    const float* v1e1      = (const float*)d_in[9];
    const float* W2        = (const float*)d_in[10];
    const float* b2        = (const float*)d_in[11];
    const float* Wd1       = (const float*)d_in[12];
    const float* bd1       = (const float*)d_in[13];
    const float* v0d1      = (const float*)d_in[14];
    const float* v1d1      = (const float*)d_in[15];
    const float* Wd2       = (const float*)d_in[16];
    const float* bd2       = (const float*)d_in[17];
    const float* Wa        = (const float*)d_in[18];
    const float* ba        = (const float*)d_in[19];
    const float* Wb        = (const float*)d_in[20];
    const float* bb        = (const float*)d_in[21];
    const float* gamma     = (const float*)d_in[22];
    const float* logtheta  = (const float*)d_in[23];
    const float* emb_table = (const float*)d_in[24];
    float* out = (float*)d_out;

    char* w = (char*)d_ws;
    auto alloc = [&](size_t bytes) { void* p = (void*)w; w += (bytes + 255) & ~(size_t)255; return p; };
    int*   col_idx = (int*)  alloc((size_t)N * CAP * 4);
    int*   row_cnt = (int*)  alloc((size_t)N * 4);
    float* bufA    = (float*)alloc((size_t)N * H1 * 4);      // Hlin (enc, then dec)
    unsigned short* Hgat_bf = (unsigned short*)alloc((size_t)N * H1 * 2);
    float* Z       = (float*)alloc((size_t)N * H2 * 4);
    unsigned short* Xd_bf   = (unsigned short*)alloc((size_t)N * KD_PAD * 2);
    unsigned short* beta_bf = (unsigned short*)alloc((size_t)N * KB_PAD * 2);
    float* muf     = (float*)alloc((size_t)N * 4);
    float* kco     = (float*)alloc((size_t)N * 4);
    float* hv0     = (float*)alloc((size_t)N * HEADS * 4);
    float* hv1     = (float*)alloc((size_t)N * HEADS * 4);
    float* th_v    = (float*)alloc((size_t)S * G * 4);
    float* aux_sg  = (float*)alloc((size_t)S * G * 4);
    float* egam    = (float*)alloc((size_t)S * G * 4);
    float* T1      = (float*)alloc((size_t)KMAX * S * G * 4);
    float* ll_part = (float*)alloc((size_t)N * 16 * 4);
    float* sq_part = (float*)alloc((size_t)N * 16 * 4);
    float* part_ll = (float*)alloc(64 * 4);
    float* part_sq = (float*)alloc(64 * 4);
    unsigned short* nf_bf    = (unsigned short*)alloc((size_t)N * G * 2);
    unsigned short* We1_bf   = (unsigned short*)alloc((size_t)H1 * G * 2);
    unsigned short* W2_bf    = (unsigned short*)alloc((size_t)H2 * H1 * 2);
    unsigned short* Wd1_bf   = (unsigned short*)alloc((size_t)H1 * KD_PAD * 2);
    unsigned short* Wd2_bf   = (unsigned short*)alloc((size_t)G * H1 * 2);
    unsigned short* basisT_bf= (unsigned short*)alloc((size_t)G * KB_PAD * 2);

    // tables + conversions
    hipLaunchKernelGGL(build_csr, dim3(N), dim3(64), 0, stream, adj, col_idx, row_cnt);
    hipLaunchKernelGGL(theta_tables, dim3((S * G + 255) / 256), dim3(256), 0, stream,
                       logtheta, gamma, th_v, aux_sg, egam);
    hipLaunchKernelGGL(t1_table, dim3((KMAX * S * G + 255) / 256), dim3(256), 0, stream,
                       th_v, aux_sg, T1);
    hipLaunchKernelGGL(f2bf_vec, dim3((N * G / 4 + 255) / 256), dim3(256), 0, stream,
                       node_f, nf_bf, N * G / 4);
    hipLaunchKernelGGL(f2bf_vec, dim3((H1 * G / 4 + 255) / 256), dim3(256), 0, stream,
                       We1, We1_bf, H1 * G / 4);
    hipLaunchKernelGGL(f2bf_vec, dim3((H2 * H1 / 4 + 255) / 256), dim3(256), 0, stream,
                       W2, W2_bf, H2 * H1 / 4);
    hipLaunchKernelGGL(convert_wd1, dim3((H1 * KD_PAD + 255) / 256), dim3(256), 0, stream,
                       Wd1, Wd1_bf);
    hipLaunchKernelGGL(f2bf_vec, dim3((G * H1 / 4 + 255) / 256), dim3(256), 0, stream,
                       Wd2, Wd2_bf, G * H1 / 4);
    hipLaunchKernelGGL(convert_basisT, dim3((G * KB_PAD + 255) / 256), dim3(256), 0, stream,
                       basis, basisT_bf);

    // 1. encoder linear
    hipLaunchKernelGGL(HIP_KERNEL_NAME(gemm_mfma<2>), dim3(H1 / 128, N / 64), dim3(256), 0, stream,
                       nf_bf, We1_bf, be1, bufA, N, H1, G);
    // 2-3. encoder attention
    hipLaunchKernelGGL(head_dots, dim3(N), dim3(64), 0, stream, bufA, v0e1, v1e1, hv0, hv1);
    hipLaunchKernelGGL(attn_agg, dim3(N), dim3(H1), 0, stream,
                       bufA, hv0, hv1, col_idx, row_cnt, Hgat_bf);
    // 4. Z
    hipLaunchKernelGGL(HIP_KERNEL_NAME(gemm_mfma<2>), dim3(H2 / 128, N / 64), dim3(256), 0, stream,
                       Hgat_bf, W2_bf, b2, Z, N, H2, H1);
    // 5. per-node
    hipLaunchKernelGGL(pernode, dim3(N), dim3(64), 0, stream,
                       Z, emb_table, slab, Wb, bb, Wa, ba, lib, beta_bf, muf, kco, Xd_bf);
    // 5b. fused NB log-likelihood (beta@basis GEMM epilogue)
    hipLaunchKernelGGL(bd_ll, dim3(G / 128, N / 128), dim3(256), 0, stream,
                       beta_bf, basisT_bf, count_m, slab, muf, kco, th_v, egam, gamma, T1, ll_part);
    // 6. decoder linear
    hipLaunchKernelGGL(HIP_KERNEL_NAME(gemm_mfma<2>), dim3(H1 / 128, N / 64), dim3(256), 0, stream,
                       Xd_bf, Wd1_bf, bd1, bufA, N, H1, KD_PAD);
    // 7-8. decoder attention
    hipLaunchKernelGGL(head_dots, dim3(N), dim3(64), 0, stream, bufA, v0d1, v1d1, hv0, hv1);
    hipLaunchKernelGGL(attn_agg, dim3(N), dim3(H1), 0, stream,
                       bufA, hv0, hv1, col_idx, row_cnt, Hgat_bf);
    // 9. fused reconstruction GEMM + sq-norm
    hipLaunchKernelGGL(gemm_recon_sq, dim3(G / 128, N / 128), dim3(256), 0, stream,
                       Hgat_bf, Wd2_bf, bd2, node_f, sq_part);
    // 10-11. reduce
    hipLaunchKernelGGL(row_reduce, dim3(64), dim3(64), 0, stream, ll_part, sq_part, part_ll, part_sq);
    hipLaunchKernelGGL(finalize2, dim3(1), dim3(64), 0, stream, part_ll, part_sq, out);
}